// Round 16
// baseline (148.989 us; speedup 1.0000x reference)
//
#include <hip/hip_runtime.h>
#include <math.h>

#define L 4096
#define C 256

typedef __attribute__((ext_vector_type(8))) short bf16x8;
typedef __attribute__((ext_vector_type(4))) short s16x4;
typedef __attribute__((ext_vector_type(4))) float f32x4;
typedef __attribute__((ext_vector_type(2))) unsigned int u32x2;
typedef __attribute__((ext_vector_type(4))) unsigned int u32x4;

#define MFMA16(a, b, c) __builtin_amdgcn_mfma_f32_16x16x32_bf16(a, b, c, 0, 0, 0)

static __device__ __forceinline__ short f2bf(float f) {
  union { float f; unsigned u; } x{f};
  unsigned r = (x.u + 0x7fffu + ((x.u >> 16) & 1u)) >> 16;
  return (short)r;
}
static __device__ __forceinline__ float bf2f(short s) {
  union { unsigned u; float f; } x{((unsigned)(unsigned short)s) << 16};
  return x.f;
}
static __device__ __forceinline__ unsigned pack2(float a, float b) {
  return (unsigned)(unsigned short)f2bf(a) | ((unsigned)(unsigned short)f2bf(b) << 16);
}
// one v_perm_b32: low16 = bf16_trunc(a), high16 = bf16_trunc(b)
static __device__ __forceinline__ unsigned ppack(float a, float b) {
  union { float f; unsigned u; } xa{a}, xb{b};
  return __builtin_amdgcn_perm(xb.u, xa.u, 0x07060302u);
}
static __device__ __forceinline__ float bflo(unsigned u) {
  union { unsigned u; float f; } x{u << 16};
  return x.f;
}
static __device__ __forceinline__ float bfhi(unsigned u) {
  union { unsigned u; float f; } x{u & 0xffff0000u};
  return x.f;
}
static __device__ __forceinline__ void gload_lds16(const void* g, void* l) {
  __builtin_amdgcn_global_load_lds(
      (const __attribute__((address_space(1))) unsigned int*)g,
      (__attribute__((address_space(3))) unsigned int*)l, 16, 0, 0);
}

// --- Kernel 0: prep = gn_stats + x->bf16 (blocks 0..511) + w2bf (512..1535) --
__global__ __launch_bounds__(256) void prep(const float* __restrict__ x,
    float* __restrict__ gnp, short* __restrict__ xbf,
    const float* __restrict__ wa, const float* __restrict__ wb,
    short* __restrict__ da, short* __restrict__ db) {
  int blk = blockIdx.x;
  int tid = threadIdx.x;
  if (blk < 512) {
    size_t base = (size_t)blk * 8192;
    const f32x4* xp = (const f32x4*)(x + base);
    u32x2* xo = (u32x2*)(xbf + base);
    float s = 0.f, ss = 0.f;
    #pragma unroll
    for (int i = 0; i < 8; ++i) {
      f32x4 v = xp[i * 256 + tid];
      s  += v[0] + v[1] + v[2] + v[3];
      ss += v[0]*v[0] + v[1]*v[1] + v[2]*v[2] + v[3]*v[3];
      u32x2 o;
      o[0] = pack2(v[0], v[1]);
      o[1] = pack2(v[2], v[3]);
      xo[i * 256 + tid] = o;
    }
    __shared__ float rs[256], rss[256];
    rs[tid] = s; rss[tid] = ss;
    __syncthreads();
    for (int off = 128; off > 0; off >>= 1) {
      if (tid < off) { rs[tid] += rs[tid + off]; rss[tid] += rss[tid + off]; }
      __syncthreads();
    }
    if (tid == 0) {
      gnp[(size_t)blk * 2]     = rs[0];
      gnp[(size_t)blk * 2 + 1] = rss[0];
    }
  } else {
    int i = (blk - 512) * 256 + tid;
    if (i < 768 * C) da[i] = f2bf(wa[i]);
    else db[i - 768 * C] = f2bf(wb[i - 768 * C]);
  }
}

// --- Kernel 1b: GroupNorm apply -> xnT bf16 [b][l][c], COALESCED writes -----
__global__ __launch_bounds__(256) void gn_apply(const short* __restrict__ xbf,
    const float* __restrict__ gw, const float* __restrict__ gb,
    const float* __restrict__ gnp, short* __restrict__ xnT) {
  int b = blockIdx.y;
  int l0 = blockIdx.x * 64;
  int tid = threadIdx.x;

  __shared__ float scl[256], sft[256];
  __shared__ short tile[64][264];    // pad 8 shorts; 33 KB

  if (tid < 32) {
    int g = tid;
    int bg = b * 32 + g;
    float s = 0.f, ss = 0.f;
    #pragma unroll
    for (int q = 0; q < 4; ++q) {
      s  += gnp[(size_t)(bg * 4 + q) * 2];
      ss += gnp[(size_t)(bg * 4 + q) * 2 + 1];
    }
    float mean = s * (1.f / 32768.f);
    float var  = ss * (1.f / 32768.f) - mean * mean;
    float rstd = rsqrtf(var + 1e-5f);
    #pragma unroll
    for (int c = 0; c < 8; ++c) {
      float wv = gw[g * 8 + c], bv = gb[g * 8 + c];
      scl[g * 8 + c] = rstd * wv;
      sft[g * 8 + c] = bv - mean * rstd * wv;
    }
  }
  __syncthreads();

  const short* xb = xbf + (size_t)b * C * L;
  #pragma unroll
  for (int p = 0; p < 16; ++p) {
    int c = p * 16 + (tid >> 4);
    int ll = (tid & 15) * 4;
    u32x2 r = *(const u32x2*)(xb + (size_t)c * L + l0 + ll);
    float sc = scl[c], sf = sft[c];
    tile[ll][c]     = f2bf(bflo(r[0]) * sc + sf);
    tile[ll + 1][c] = f2bf(bfhi(r[0]) * sc + sf);
    tile[ll + 2][c] = f2bf(bflo(r[1]) * sc + sf);
    tile[ll + 3][c] = f2bf(bfhi(r[1]) * sc + sf);
  }
  __syncthreads();

  short* ob = xnT + ((size_t)b * L + l0) * C;
  int lrow = tid >> 2, ch = tid & 3;
  #pragma unroll
  for (int k = 0; k < 8; ++k) {
    int c0 = ch * 8 + k * 32;
    u32x4 v = *(const u32x4*)&tile[lrow][c0];
    *(u32x4*)(ob + (size_t)lrow * C + c0) = v;
  }
}

// ------------- Kernel 2: QKV MFMA GEMM, LDS-bounce coalesced epilogue ------
__global__ __launch_bounds__(256) void qkv_mfma(const short* __restrict__ wq,
    const float* __restrict__ bias, const short* __restrict__ xnT,
    short* __restrict__ qT, short* __restrict__ kT, short* __restrict__ vB) {
  int tid = threadIdx.x;
  int wid = tid >> 6, lane = tid & 63, g = lane >> 4, lr = lane & 15;
  int oy = blockIdx.y;
  int o0 = oy * 64;
  int b  = blockIdx.z;
  int head = oy / 3, kind = oy % 3;
  int bh = b * 4 + head;
  int lw = blockIdx.x * 128 + wid * 32;
  int lwb = blockIdx.x * 128;
  const short* xb = xnT + (size_t)b * L * C;

  __shared__ short obuf[128 * 72];   // 18.4 KB bounce

  f32x4 acc[4][2];
  #pragma unroll
  for (int m = 0; m < 4; ++m)
    #pragma unroll
    for (int nt = 0; nt < 2; ++nt) acc[m][nt] = (f32x4)0.f;

  #pragma unroll 2
  for (int k0 = 0; k0 < C; k0 += 32) {
    bf16x8 af[4], bfr[2];
    #pragma unroll
    for (int m = 0; m < 4; ++m)
      af[m] = *(const bf16x8*)(wq + (size_t)(o0 + m * 16 + lr) * C + k0 + g * 8);
    #pragma unroll
    for (int nt = 0; nt < 2; ++nt)
      bfr[nt] = *(const bf16x8*)(xb + (size_t)(lw + nt * 16 + lr) * C + k0 + g * 8);
    #pragma unroll
    for (int m = 0; m < 4; ++m)
      #pragma unroll
      for (int nt = 0; nt < 2; ++nt)
        acc[m][nt] = MFMA16(af[m], bfr[nt], acc[m][nt]);
  }

  float sc = (kind == 0) ? 0.51014930f : (kind == 1) ? 0.35355339f : 1.0f;
  if (kind == 2) {
    #pragma unroll
    for (int m = 0; m < 4; ++m)
      #pragma unroll
      for (int nt = 0; nt < 2; ++nt) {
        int l = wid * 32 + nt * 16 + lr;
        #pragma unroll
        for (int r = 0; r < 4; ++r) {
          int o = m * 16 + g * 4 + r;
          obuf[o * 136 + l] = f2bf(acc[m][nt][r] + bias[o0 + o]);
        }
      }
    __syncthreads();
    int o = tid >> 2, ch = tid & 3;
    #pragma unroll
    for (int k = 0; k < 4; ++k) {
      int c0 = ch * 8 + k * 32;
      u32x4 v = *(const u32x4*)&obuf[o * 136 + c0];
      *(u32x4*)(vB + ((size_t)bh * 64 + o) * L + lwb + c0) = v;
    }
  } else {
    short* dst = (kind == 0 ? qT : kT);
    #pragma unroll
    for (int m = 0; m < 4; ++m)
      #pragma unroll
      for (int nt = 0; nt < 2; ++nt) {
        int l = wid * 32 + nt * 16 + lr;
        s16x4 pk;
        #pragma unroll
        for (int r = 0; r < 4; ++r)
          pk[r] = f2bf((acc[m][nt][r] + bias[o0 + m * 16 + g * 4 + r]) * sc);
        *(s16x4*)&obuf[l * 72 + m * 16 + g * 4] = pk;
      }
    __syncthreads();
    short* db2 = dst + ((size_t)bh * L + lwb) * 64;
    #pragma unroll
    for (int p = 0; p < 4; ++p) {
      int idx = p * 2048 + tid * 8;
      int l = idx >> 6, c = idx & 63;
      u32x4 v = *(const u32x4*)&obuf[l * 72 + c];
      *(u32x4*)(db2 + idx) = v;
    }
  }
}

// ------------- Kernel 3: MFMA flash attention (R9/R13 best: 90 us) ---------
__global__ __launch_bounds__(512) void attn_mfma(
    const short* __restrict__ qT, const short* __restrict__ kT,
    const short* __restrict__ vB, short* __restrict__ amatT) {
  int orig = blockIdx.x;
  int bid = (orig & 7) * 32 + (orig >> 3);   // 256 % 8 == 0, bijective
  int bh = bid >> 4, qb = bid & 15;
  int b = bh >> 2, h = bh & 3;
  int tid = threadIdx.x;
  int wid = tid >> 6, lane = tid & 63;
  int g = lane >> 4, lr = lane & 15;
  int tw = qb * 256 + wid * 32;
  int lx7 = lr & 7;
  int pswA = ((lr & 3) << 4) | ((lr >> 2) << 2);

  const short* qTh = qT + (size_t)bh * L * 64;
  const short* kTh = kT + (size_t)bh * L * 64;
  const short* vh  = vB + (size_t)bh * 64 * L;

  __shared__ short Kt[4][64 * 64];
  __shared__ short Vt[4][64 * 64];
  __shared__ short plds[8][32][64];

  bf16x8 qf[2][2];
  #pragma unroll
  for (int nt = 0; nt < 2; ++nt)
    #pragma unroll
    for (int ks = 0; ks < 2; ++ks)
      qf[nt][ks] = *(const bf16x8*)(qTh + (size_t)(tw + nt * 16 + lr) * 64 +
                                    ks * 32 + g * 8);

  bf16x8 ones;
  #pragma unroll
  for (int i = 0; i < 8; ++i) ones[i] = (short)0x3F80;

  f32x4 acc[4][2], acc_l[2];
  #pragma unroll
  for (int cm = 0; cm < 4; ++cm)
    #pragma unroll
    for (int nt = 0; nt < 2; ++nt) acc[cm][nt] = (f32x4)0.f;
  acc_l[0] = (f32x4)0.f; acc_l[1] = (f32x4)0.f;

  size_t koff, voff;
  int ldsc;
  {
    int r = tid >> 3, c16 = tid & 7;
    int cs = c16 ^ (r & 7);
    koff = (size_t)r * 64 + cs * 8;
    voff = (size_t)r * L + cs * 8;
    ldsc = wid * 512;
  }

  gload_lds16(kTh + koff, &Kt[0][ldsc]);
  gload_lds16(vh + voff, &Vt[0][ldsc]);
  gload_lds16(kTh + koff + (size_t)64 * 64, &Kt[1][ldsc]);
  gload_lds16(vh + voff + 64, &Vt[1][ldsc]);

  int sl = 0;
  #pragma unroll 1
  for (int s = 0; s < 32; ++s) {
    if (s < 31) {
      int nb = sl ^ 2;
      size_t t0 = (size_t)(2 * s + 2) * 64, t1 = (size_t)(2 * s + 3) * 64;
      gload_lds16(kTh + koff + t0 * 64, &Kt[nb][ldsc]);
      gload_lds16(vh + voff + t0, &Vt[nb][ldsc]);
      gload_lds16(kTh + koff + t1 * 64, &Kt[nb + 1][ldsc]);
      gload_lds16(vh + voff + t1, &Vt[nb + 1][ldsc]);
      asm volatile("s_waitcnt vmcnt(4)" ::: "memory");
    } else {
      asm volatile("s_waitcnt vmcnt(0)" ::: "memory");
    }
    __builtin_amdgcn_sched_barrier(0);
    __builtin_amdgcn_s_barrier();

    const short* Ka = &Kt[sl][0];     const short* Va = &Vt[sl][0];
    const short* Kb = &Kt[sl + 1][0]; const short* Vb = &Vt[sl + 1][0];

    f32x4 st0[4][2], st1[4][2];
    __builtin_amdgcn_s_setprio(1);
    #pragma unroll
    for (int sm = 0; sm < 4; ++sm) {
      int row = sm * 16 + lr;
      bf16x8 kf0 = *(const bf16x8*)&Ka[row * 64 + ((g ^ lx7)) * 8];
      bf16x8 kf1 = *(const bf16x8*)&Ka[row * 64 + (((4 + g) ^ lx7)) * 8];
      #pragma unroll
      for (int nt = 0; nt < 2; ++nt) {
        f32x4 cc = (f32x4)0.f;
        cc = MFMA16(kf0, qf[nt][0], cc);
        cc = MFMA16(kf1, qf[nt][1], cc);
        st0[sm][nt] = cc;
      }
    }
    __builtin_amdgcn_s_setprio(0);
    #pragma unroll
    for (int sm = 0; sm < 4; ++sm) {
      int row = sm * 16 + lr;
      bf16x8 kf0 = *(const bf16x8*)&Kb[row * 64 + ((g ^ lx7)) * 8];
      bf16x8 kf1 = *(const bf16x8*)&Kb[row * 64 + (((4 + g) ^ lx7)) * 8];
      #pragma unroll
      for (int nt = 0; nt < 2; ++nt) {
        f32x4 cc = (f32x4)0.f;
        cc = MFMA16(kf0, qf[nt][0], cc);
        cc = MFMA16(kf1, qf[nt][1], cc);
        st1[sm][nt] = cc;
        u32x2 w;
        w[0] = ppack(__builtin_amdgcn_exp2f(st0[sm][nt][0]),
                     __builtin_amdgcn_exp2f(st0[sm][nt][1]));
        w[1] = ppack(__builtin_amdgcn_exp2f(st0[sm][nt][2]),
                     __builtin_amdgcn_exp2f(st0[sm][nt][3]));
        *(u32x2*)&plds[wid][nt * 16 + lr][(sm * 16 + g * 4) ^ pswA] = w;
      }
    }
    bf16x8 pf0[2][2];
    #pragma unroll
    for (int nt = 0; nt < 2; ++nt)
      #pragma unroll
      for (int ks = 0; ks < 2; ++ks) {
        s16x4 pa = *(const s16x4*)&plds[wid][nt * 16 + lr][(ks * 32 + g * 8) ^ pswA];
        s16x4 pb = *(const s16x4*)&plds[wid][nt * 16 + lr][(ks * 32 + g * 8 + 4) ^ pswA];
        pf0[nt][ks] = __builtin_shufflevector(pa, pb, 0, 1, 2, 3, 4, 5, 6, 7);
      }
    #pragma unroll
    for (int nt = 0; nt < 2; ++nt) {
      acc_l[nt] = MFMA16(ones, pf0[nt][0], acc_l[nt]);
      acc_l[nt] = MFMA16(ones, pf0[nt][1], acc_l[nt]);
    }
    #pragma unroll
    for (int cm = 0; cm < 4; ++cm) {
      int row = cm * 16 + lr;
      bf16x8 vf0 = *(const bf16x8*)&Va[row * 64 + ((g ^ lx7)) * 8];
      bf16x8 vf1 = *(const bf16x8*)&Va[row * 64 + (((4 + g) ^ lx7)) * 8];
      #pragma unroll
      for (int nt = 0; nt < 2; ++nt) {
        acc[cm][nt] = MFMA16(vf0, pf0[nt][0], acc[cm][nt]);
        acc[cm][nt] = MFMA16(vf1, pf0[nt][1], acc[cm][nt]);
        u32x2 w;
        w[0] = ppack(__builtin_amdgcn_exp2f(st1[cm][nt][0]),
                     __builtin_amdgcn_exp2f(st1[cm][nt][1]));
        w[1] = ppack(__builtin_amdgcn_exp2f(st1[cm][nt][2]),
                     __builtin_amdgcn_exp2f(st1[cm][nt][3]));
        *(u32x2*)&plds[wid][nt * 16 + lr][(cm * 16 + g * 4) ^ pswA] = w;
      }
    }
    bf16x8 pf1[2][2];
    #pragma unroll
    for (int nt = 0; nt < 2; ++nt)
      #pragma unroll
      for (int ks = 0; ks < 2; ++ks) {
        s16x4 pa = *(const s16x4*)&plds[wid][nt * 16 + lr][(ks * 32 + g * 8) ^ pswA];
        s16x4 pb = *(const s16x4*)&plds[wid][nt * 16 + lr][(ks * 32 + g * 8 + 4) ^ pswA];
        pf1[nt][ks] = __builtin_shufflevector(pa, pb, 0, 1, 2, 3, 4, 5, 6, 7);
      }
    __builtin_amdgcn_s_setprio(1);
    #pragma unroll
    for (int nt = 0; nt < 2; ++nt) {
      acc_l[nt] = MFMA16(ones, pf1[nt][0], acc_l[nt]);
      acc_l[nt] = MFMA16(ones, pf1[nt][1], acc_l[nt]);
    }
    #pragma unroll
    for (int cm = 0; cm < 4; ++cm) {
      int row = cm * 16 + lr;
      bf16x8 vf0 = *(const bf16x8*)&Vb[row * 64 + ((g ^ lx7)) * 8];
      bf16x8 vf1 = *(const bf16x8*)&Vb[row * 64 + (((4 + g) ^ lx7)) * 8];
      #pragma unroll
      for (int nt = 0; nt < 2; ++nt) {
        acc[cm][nt] = MFMA16(vf0, pf1[nt][0], acc[cm][nt]);
        acc[cm][nt] = MFMA16(vf1, pf1[nt][1], acc[cm][nt]);
      }
    }
    __builtin_amdgcn_s_setprio(0);
    __builtin_amdgcn_s_barrier();
    sl ^= 2;
  }

  #pragma unroll
  for (int nt = 0; nt < 2; ++nt) {
    float inv = 1.f / acc_l[nt][0];
    #pragma unroll
    for (int cm = 0; cm < 4; ++cm) {
      s16x4 pk;
      #pragma unroll
      for (int r = 0; r < 4; ++r) pk[r] = f2bf(acc[cm][nt][r] * inv);
      *(s16x4*)(amatT + ((size_t)b * L + tw + nt * 16 + lr) * C + h * 64 +
                cm * 16 + g * 4) = pk;
    }
  }
}

// --- Kernel 4: proj MFMA GEMM + bias + residual (residual from bf16 xbf) ---
__global__ __launch_bounds__(256) void proj_mfma(const short* __restrict__ pw,
    const float* __restrict__ bias, const short* __restrict__ amatT,
    const short* __restrict__ xbf, float* __restrict__ out) {
  int tid = threadIdx.x;
  int wid = tid >> 6, lane = tid & 63, g = lane >> 4, lr = lane & 15;
  int o0 = blockIdx.y * 64;
  int b  = blockIdx.z;
  int lw = blockIdx.x * 128 + wid * 32;
  const short* ab = amatT + (size_t)b * L * C;

  f32x4 acc[4][2];
  #pragma unroll
  for (int m = 0; m < 4; ++m)
    #pragma unroll
    for (int nt = 0; nt < 2; ++nt) acc[m][nt] = (f32x4)0.f;

  #pragma unroll 2
  for (int k0 = 0; k0 < C; k0 += 32) {
    bf16x8 af[4], bfr[2];
    #pragma unroll
    for (int m = 0; m < 4; ++m)
      af[m] = *(const bf16x8*)(pw + (size_t)(o0 + m * 16 + lr) * C + k0 + g * 8);
    #pragma unroll
    for (int nt = 0; nt < 2; ++nt)
      bfr[nt] = *(const bf16x8*)(ab + (size_t)(lw + nt * 16 + lr) * C + k0 + g * 8);
    #pragma unroll
    for (int m = 0; m < 4; ++m)
      #pragma unroll
      for (int nt = 0; nt < 2; ++nt)
        acc[m][nt] = MFMA16(af[m], bfr[nt], acc[m][nt]);
  }

  #pragma unroll
  for (int m = 0; m < 4; ++m)
    #pragma unroll
    for (int nt = 0; nt < 2; ++nt)
      #pragma unroll
      for (int r = 0; r < 4; ++r) {
        int o = o0 + m * 16 + g * 4 + r;
        size_t idx = ((size_t)b * C + o) * L + lw + nt * 16 + lr;
        out[idx] = acc[m][nt][r] + bias[o] + bf2f(xbf[idx]);
      }
}

// ---------------------------- launcher ----------------------------
extern "C" void kernel_launch(void* const* d_in, const int* in_sizes, int n_in,
                              void* d_out, int out_size, void* d_ws, size_t ws_size,
                              hipStream_t stream) {
  const float* x      = (const float*)d_in[0];
  const float* gn_w   = (const float*)d_in[1];
  const float* gn_b   = (const float*)d_in[2];
  const float* qkv_w  = (const float*)d_in[3];
  const float* qkv_b  = (const float*)d_in[4];
  const float* proj_w = (const float*)d_in[5];
  const float* proj_b = (const float*)d_in[6];
  float* out = (float*)d_out;

  short* xnT   = (short*)d_ws;                        // 8 MB
  short* qT    = xnT   + (size_t)4 * L * C;           // 8 MB
  short* kT    = qT    + (size_t)16 * L * 64;         // 8 MB
  short* vB    = kT    + (size_t)16 * L * 64;         // 8 MB
  short* amatT = vB    + (size_t)16 * L * 64;         // 8 MB
  short* xbf   = amatT + (size_t)4 * L * C;           // 8 MB
  short* wqbf  = xbf   + (size_t)4 * C * L;           // 384 KB
  short* pwbf  = wqbf  + (size_t)768 * C;             // 128 KB
  float* gnp   = (float*)(pwbf + (size_t)C * C);      // 4 KB

  prep<<<1536, 256, 0, stream>>>(x, gnp, xbf, qkv_w, proj_w, wqbf, pwbf);
  gn_apply<<<dim3(64, 4), 256, 0, stream>>>(xbf, gn_w, gn_b, gnp, xnT);
  qkv_mfma<<<dim3(32, 12, 4), 256, 0, stream>>>(wqbf, qkv_b, xnT, qT, kT, vB);
  attn_mfma<<<256, 512, 0, stream>>>(qT, kT, vB, amatT);
  proj_mfma<<<dim3(32, 4, 4), 256, 0, stream>>>(pwbf, proj_b, amatT, xbf, out);
}

// Round 17
// 145.152 us; speedup vs baseline: 1.0264x; 1.0264x over previous
//
#include <hip/hip_runtime.h>
#include <math.h>

#define L 4096
#define C 256

typedef __attribute__((ext_vector_type(8))) short bf16x8;
typedef __attribute__((ext_vector_type(4))) short s16x4;
typedef __attribute__((ext_vector_type(4))) float f32x4;
typedef __attribute__((ext_vector_type(2))) unsigned int u32x2;
typedef __attribute__((ext_vector_type(4))) unsigned int u32x4;

#define MFMA16(a, b, c) __builtin_amdgcn_mfma_f32_16x16x32_bf16(a, b, c, 0, 0, 0)

static __device__ __forceinline__ short f2bf(float f) {
  union { float f; unsigned u; } x{f};
  unsigned r = (x.u + 0x7fffu + ((x.u >> 16) & 1u)) >> 16;
  return (short)r;
}
static __device__ __forceinline__ unsigned pack2(float a, float b) {
  return (unsigned)(unsigned short)f2bf(a) | ((unsigned)(unsigned short)f2bf(b) << 16);
}
// one v_perm_b32: low16 = bf16_trunc(a), high16 = bf16_trunc(b)
static __device__ __forceinline__ unsigned ppack(float a, float b) {
  union { float f; unsigned u; } xa{a}, xb{b};
  return __builtin_amdgcn_perm(xb.u, xa.u, 0x07060302u);
}
static __device__ __forceinline__ float bflo(unsigned u) {
  union { unsigned u; float f; } x{u << 16};
  return x.f;
}
static __device__ __forceinline__ float bfhi(unsigned u) {
  union { unsigned u; float f; } x{u & 0xffff0000u};
  return x.f;
}
static __device__ __forceinline__ void gload_lds16(const void* g, void* l) {
  __builtin_amdgcn_global_load_lds(
      (const __attribute__((address_space(1))) unsigned int*)g,
      (__attribute__((address_space(3))) unsigned int*)l, 16, 0, 0);
}

// --- Kernel 0: prep = gn_stats + x->bf16 (blocks 0..511) + w2bf (512..1535) --
__global__ __launch_bounds__(256) void prep(const float* __restrict__ x,
    float* __restrict__ gnp, short* __restrict__ xbf,
    const float* __restrict__ wa, const float* __restrict__ wb,
    short* __restrict__ da, short* __restrict__ db) {
  int blk = blockIdx.x;
  int tid = threadIdx.x;
  if (blk < 512) {
    size_t base = (size_t)blk * 8192;
    const f32x4* xp = (const f32x4*)(x + base);
    u32x2* xo = (u32x2*)(xbf + base);
    float s = 0.f, ss = 0.f;
    #pragma unroll
    for (int i = 0; i < 8; ++i) {
      f32x4 v = xp[i * 256 + tid];
      s  += v[0] + v[1] + v[2] + v[3];
      ss += v[0]*v[0] + v[1]*v[1] + v[2]*v[2] + v[3]*v[3];
      u32x2 o;
      o[0] = pack2(v[0], v[1]);
      o[1] = pack2(v[2], v[3]);
      xo[i * 256 + tid] = o;
    }
    __shared__ float rs[256], rss[256];
    rs[tid] = s; rss[tid] = ss;
    __syncthreads();
    for (int off = 128; off > 0; off >>= 1) {
      if (tid < off) { rs[tid] += rs[tid + off]; rss[tid] += rss[tid + off]; }
      __syncthreads();
    }
    if (tid == 0) {
      gnp[(size_t)blk * 2]     = rs[0];
      gnp[(size_t)blk * 2 + 1] = rss[0];
    }
  } else {
    int i = (blk - 512) * 256 + tid;
    if (i < 768 * C) da[i] = f2bf(wa[i]);
    else db[i - 768 * C] = f2bf(wb[i - 768 * C]);
  }
}

// --- Kernel 1b: GroupNorm apply -> xnT bf16 [b][l][c], COALESCED writes -----
__global__ __launch_bounds__(256) void gn_apply(const short* __restrict__ xbf,
    const float* __restrict__ gw, const float* __restrict__ gb,
    const float* __restrict__ gnp, short* __restrict__ xnT) {
  int b = blockIdx.y;
  int l0 = blockIdx.x * 64;
  int tid = threadIdx.x;

  __shared__ float scl[256], sft[256];
  __shared__ short tile[64][264];    // pad 8 shorts; 33 KB

  if (tid < 32) {
    int g = tid;
    int bg = b * 32 + g;
    float s = 0.f, ss = 0.f;
    #pragma unroll
    for (int q = 0; q < 4; ++q) {
      s  += gnp[(size_t)(bg * 4 + q) * 2];
      ss += gnp[(size_t)(bg * 4 + q) * 2 + 1];
    }
    float mean = s * (1.f / 32768.f);
    float var  = ss * (1.f / 32768.f) - mean * mean;
    float rstd = rsqrtf(var + 1e-5f);
    #pragma unroll
    for (int c = 0; c < 8; ++c) {
      float wv = gw[g * 8 + c], bv = gb[g * 8 + c];
      scl[g * 8 + c] = rstd * wv;
      sft[g * 8 + c] = bv - mean * rstd * wv;
    }
  }
  __syncthreads();

  const short* xb = xbf + (size_t)b * C * L;
  #pragma unroll
  for (int p = 0; p < 16; ++p) {
    int c = p * 16 + (tid >> 4);
    int ll = (tid & 15) * 4;
    u32x2 r = *(const u32x2*)(xb + (size_t)c * L + l0 + ll);
    float sc = scl[c], sf = sft[c];
    tile[ll][c]     = f2bf(bflo(r[0]) * sc + sf);
    tile[ll + 1][c] = f2bf(bfhi(r[0]) * sc + sf);
    tile[ll + 2][c] = f2bf(bflo(r[1]) * sc + sf);
    tile[ll + 3][c] = f2bf(bfhi(r[1]) * sc + sf);
  }
  __syncthreads();

  short* ob = xnT + ((size_t)b * L + l0) * C;
  int lrow = tid >> 2, ch = tid & 3;
  #pragma unroll
  for (int k = 0; k < 8; ++k) {
    int c0 = ch * 8 + k * 32;
    u32x4 v = *(const u32x4*)&tile[lrow][c0];
    *(u32x4*)(ob + (size_t)lrow * C + c0) = v;
  }
}

// ------------- Kernel 2: QKV MFMA GEMM, LDS-bounce coalesced epilogue ------
__global__ __launch_bounds__(256) void qkv_mfma(const short* __restrict__ wq,
    const float* __restrict__ bias, const short* __restrict__ xnT,
    short* __restrict__ qT, short* __restrict__ kT, short* __restrict__ vB) {
  int tid = threadIdx.x;
  int wid = tid >> 6, lane = tid & 63, g = lane >> 4, lr = lane & 15;
  int oy = blockIdx.y;
  int o0 = oy * 64;
  int b  = blockIdx.z;
  int head = oy / 3, kind = oy % 3;
  int bh = b * 4 + head;
  int lw = blockIdx.x * 128 + wid * 32;
  int lwb = blockIdx.x * 128;
  const short* xb = xnT + (size_t)b * L * C;

  __shared__ short obuf[128 * 72];   // 18.4 KB bounce

  f32x4 acc[4][2];
  #pragma unroll
  for (int m = 0; m < 4; ++m)
    #pragma unroll
    for (int nt = 0; nt < 2; ++nt) acc[m][nt] = (f32x4)0.f;

  #pragma unroll 2
  for (int k0 = 0; k0 < C; k0 += 32) {
    bf16x8 af[4], bfr[2];
    #pragma unroll
    for (int m = 0; m < 4; ++m)
      af[m] = *(const bf16x8*)(wq + (size_t)(o0 + m * 16 + lr) * C + k0 + g * 8);
    #pragma unroll
    for (int nt = 0; nt < 2; ++nt)
      bfr[nt] = *(const bf16x8*)(xb + (size_t)(lw + nt * 16 + lr) * C + k0 + g * 8);
    #pragma unroll
    for (int m = 0; m < 4; ++m)
      #pragma unroll
      for (int nt = 0; nt < 2; ++nt)
        acc[m][nt] = MFMA16(af[m], bfr[nt], acc[m][nt]);
  }

  float sc = (kind == 0) ? 0.51014930f : (kind == 1) ? 0.35355339f : 1.0f;
  if (kind == 2) {
    #pragma unroll
    for (int m = 0; m < 4; ++m)
      #pragma unroll
      for (int nt = 0; nt < 2; ++nt) {
        int l = wid * 32 + nt * 16 + lr;
        #pragma unroll
        for (int r = 0; r < 4; ++r) {
          int o = m * 16 + g * 4 + r;
          obuf[o * 136 + l] = f2bf(acc[m][nt][r] + bias[o0 + o]);
        }
      }
    __syncthreads();
    int o = tid >> 2, ch = tid & 3;
    #pragma unroll
    for (int k = 0; k < 4; ++k) {
      int c0 = ch * 8 + k * 32;
      u32x4 v = *(const u32x4*)&obuf[o * 136 + c0];
      *(u32x4*)(vB + ((size_t)bh * 64 + o) * L + lwb + c0) = v;
    }
  } else {
    short* dst = (kind == 0 ? qT : kT);
    #pragma unroll
    for (int m = 0; m < 4; ++m)
      #pragma unroll
      for (int nt = 0; nt < 2; ++nt) {
        int l = wid * 32 + nt * 16 + lr;
        s16x4 pk;
        #pragma unroll
        for (int r = 0; r < 4; ++r)
          pk[r] = f2bf((acc[m][nt][r] + bias[o0 + m * 16 + g * 4 + r]) * sc);
        *(s16x4*)&obuf[l * 72 + m * 16 + g * 4] = pk;
      }
    __syncthreads();
    short* db2 = dst + ((size_t)bh * L + lwb) * 64;
    #pragma unroll
    for (int p = 0; p < 4; ++p) {
      int idx = p * 2048 + tid * 8;
      int l = idx >> 6, c = idx & 63;
      u32x4 v = *(const u32x4*)&obuf[l * 72 + c];
      *(u32x4*)(db2 + idx) = v;
    }
  }
}

// ------------- Kernel 3: MFMA flash attention (R9/R13 best: 90 us) ---------
__global__ __launch_bounds__(512) void attn_mfma(
    const short* __restrict__ qT, const short* __restrict__ kT,
    const short* __restrict__ vB, short* __restrict__ amatT) {
  int orig = blockIdx.x;
  int bid = (orig & 7) * 32 + (orig >> 3);   // 256 % 8 == 0, bijective
  int bh = bid >> 4, qb = bid & 15;
  int b = bh >> 2, h = bh & 3;
  int tid = threadIdx.x;
  int wid = tid >> 6, lane = tid & 63;
  int g = lane >> 4, lr = lane & 15;
  int tw = qb * 256 + wid * 32;
  int lx7 = lr & 7;
  int pswA = ((lr & 3) << 4) | ((lr >> 2) << 2);

  const short* qTh = qT + (size_t)bh * L * 64;
  const short* kTh = kT + (size_t)bh * L * 64;
  const short* vh  = vB + (size_t)bh * 64 * L;

  __shared__ short Kt[4][64 * 64];
  __shared__ short Vt[4][64 * 64];
  __shared__ short plds[8][32][64];

  bf16x8 qf[2][2];
  #pragma unroll
  for (int nt = 0; nt < 2; ++nt)
    #pragma unroll
    for (int ks = 0; ks < 2; ++ks)
      qf[nt][ks] = *(const bf16x8*)(qTh + (size_t)(tw + nt * 16 + lr) * 64 +
                                    ks * 32 + g * 8);

  bf16x8 ones;
  #pragma unroll
  for (int i = 0; i < 8; ++i) ones[i] = (short)0x3F80;

  f32x4 acc[4][2], acc_l[2];
  #pragma unroll
  for (int cm = 0; cm < 4; ++cm)
    #pragma unroll
    for (int nt = 0; nt < 2; ++nt) acc[cm][nt] = (f32x4)0.f;
  acc_l[0] = (f32x4)0.f; acc_l[1] = (f32x4)0.f;

  size_t koff, voff;
  int ldsc;
  {
    int r = tid >> 3, c16 = tid & 7;
    int cs = c16 ^ (r & 7);
    koff = (size_t)r * 64 + cs * 8;
    voff = (size_t)r * L + cs * 8;
    ldsc = wid * 512;
  }

  gload_lds16(kTh + koff, &Kt[0][ldsc]);
  gload_lds16(vh + voff, &Vt[0][ldsc]);
  gload_lds16(kTh + koff + (size_t)64 * 64, &Kt[1][ldsc]);
  gload_lds16(vh + voff + 64, &Vt[1][ldsc]);

  int sl = 0;
  #pragma unroll 1
  for (int s = 0; s < 32; ++s) {
    if (s < 31) {
      int nb = sl ^ 2;
      size_t t0 = (size_t)(2 * s + 2) * 64, t1 = (size_t)(2 * s + 3) * 64;
      gload_lds16(kTh + koff + t0 * 64, &Kt[nb][ldsc]);
      gload_lds16(vh + voff + t0, &Vt[nb][ldsc]);
      gload_lds16(kTh + koff + t1 * 64, &Kt[nb + 1][ldsc]);
      gload_lds16(vh + voff + t1, &Vt[nb + 1][ldsc]);
      asm volatile("s_waitcnt vmcnt(4)" ::: "memory");
    } else {
      asm volatile("s_waitcnt vmcnt(0)" ::: "memory");
    }
    __builtin_amdgcn_sched_barrier(0);
    __builtin_amdgcn_s_barrier();

    const short* Ka = &Kt[sl][0];     const short* Va = &Vt[sl][0];
    const short* Kb = &Kt[sl + 1][0]; const short* Vb = &Vt[sl + 1][0];

    f32x4 st0[4][2], st1[4][2];
    __builtin_amdgcn_s_setprio(1);
    #pragma unroll
    for (int sm = 0; sm < 4; ++sm) {
      int row = sm * 16 + lr;
      bf16x8 kf0 = *(const bf16x8*)&Ka[row * 64 + ((g ^ lx7)) * 8];
      bf16x8 kf1 = *(const bf16x8*)&Ka[row * 64 + (((4 + g) ^ lx7)) * 8];
      #pragma unroll
      for (int nt = 0; nt < 2; ++nt) {
        f32x4 cc = (f32x4)0.f;
        cc = MFMA16(kf0, qf[nt][0], cc);
        cc = MFMA16(kf1, qf[nt][1], cc);
        st0[sm][nt] = cc;
      }
    }
    __builtin_amdgcn_s_setprio(0);
    #pragma unroll
    for (int sm = 0; sm < 4; ++sm) {
      int row = sm * 16 + lr;
      bf16x8 kf0 = *(const bf16x8*)&Kb[row * 64 + ((g ^ lx7)) * 8];
      bf16x8 kf1 = *(const bf16x8*)&Kb[row * 64 + (((4 + g) ^ lx7)) * 8];
      #pragma unroll
      for (int nt = 0; nt < 2; ++nt) {
        f32x4 cc = (f32x4)0.f;
        cc = MFMA16(kf0, qf[nt][0], cc);
        cc = MFMA16(kf1, qf[nt][1], cc);
        st1[sm][nt] = cc;
        u32x2 w;
        w[0] = ppack(__builtin_amdgcn_exp2f(st0[sm][nt][0]),
                     __builtin_amdgcn_exp2f(st0[sm][nt][1]));
        w[1] = ppack(__builtin_amdgcn_exp2f(st0[sm][nt][2]),
                     __builtin_amdgcn_exp2f(st0[sm][nt][3]));
        *(u32x2*)&plds[wid][nt * 16 + lr][(sm * 16 + g * 4) ^ pswA] = w;
      }
    }
    bf16x8 pf0[2][2];
    #pragma unroll
    for (int nt = 0; nt < 2; ++nt)
      #pragma unroll
      for (int ks = 0; ks < 2; ++ks) {
        s16x4 pa = *(const s16x4*)&plds[wid][nt * 16 + lr][(ks * 32 + g * 8) ^ pswA];
        s16x4 pb = *(const s16x4*)&plds[wid][nt * 16 + lr][(ks * 32 + g * 8 + 4) ^ pswA];
        pf0[nt][ks] = __builtin_shufflevector(pa, pb, 0, 1, 2, 3, 4, 5, 6, 7);
      }
    #pragma unroll
    for (int nt = 0; nt < 2; ++nt) {
      acc_l[nt] = MFMA16(ones, pf0[nt][0], acc_l[nt]);
      acc_l[nt] = MFMA16(ones, pf0[nt][1], acc_l[nt]);
    }
    #pragma unroll
    for (int cm = 0; cm < 4; ++cm) {
      int row = cm * 16 + lr;
      bf16x8 vf0 = *(const bf16x8*)&Va[row * 64 + ((g ^ lx7)) * 8];
      bf16x8 vf1 = *(const bf16x8*)&Va[row * 64 + (((4 + g) ^ lx7)) * 8];
      #pragma unroll
      for (int nt = 0; nt < 2; ++nt) {
        acc[cm][nt] = MFMA16(vf0, pf0[nt][0], acc[cm][nt]);
        acc[cm][nt] = MFMA16(vf1, pf0[nt][1], acc[cm][nt]);
        u32x2 w;
        w[0] = ppack(__builtin_amdgcn_exp2f(st1[cm][nt][0]),
                     __builtin_amdgcn_exp2f(st1[cm][nt][1]));
        w[1] = ppack(__builtin_amdgcn_exp2f(st1[cm][nt][2]),
                     __builtin_amdgcn_exp2f(st1[cm][nt][3]));
        *(u32x2*)&plds[wid][nt * 16 + lr][(cm * 16 + g * 4) ^ pswA] = w;
      }
    }
    bf16x8 pf1[2][2];
    #pragma unroll
    for (int nt = 0; nt < 2; ++nt)
      #pragma unroll
      for (int ks = 0; ks < 2; ++ks) {
        s16x4 pa = *(const s16x4*)&plds[wid][nt * 16 + lr][(ks * 32 + g * 8) ^ pswA];
        s16x4 pb = *(const s16x4*)&plds[wid][nt * 16 + lr][(ks * 32 + g * 8 + 4) ^ pswA];
        pf1[nt][ks] = __builtin_shufflevector(pa, pb, 0, 1, 2, 3, 4, 5, 6, 7);
      }
    __builtin_amdgcn_s_setprio(1);
    #pragma unroll
    for (int nt = 0; nt < 2; ++nt) {
      acc_l[nt] = MFMA16(ones, pf1[nt][0], acc_l[nt]);
      acc_l[nt] = MFMA16(ones, pf1[nt][1], acc_l[nt]);
    }
    #pragma unroll
    for (int cm = 0; cm < 4; ++cm) {
      int row = cm * 16 + lr;
      bf16x8 vf0 = *(const bf16x8*)&Vb[row * 64 + ((g ^ lx7)) * 8];
      bf16x8 vf1 = *(const bf16x8*)&Vb[row * 64 + (((4 + g) ^ lx7)) * 8];
      #pragma unroll
      for (int nt = 0; nt < 2; ++nt) {
        acc[cm][nt] = MFMA16(vf0, pf1[nt][0], acc[cm][nt]);
        acc[cm][nt] = MFMA16(vf1, pf1[nt][1], acc[cm][nt]);
      }
    }
    __builtin_amdgcn_s_setprio(0);
    __builtin_amdgcn_s_barrier();
    sl ^= 2;
  }

  #pragma unroll
  for (int nt = 0; nt < 2; ++nt) {
    float inv = 1.f / acc_l[nt][0];
    #pragma unroll
    for (int cm = 0; cm < 4; ++cm) {
      s16x4 pk;
      #pragma unroll
      for (int r = 0; r < 4; ++r) pk[r] = f2bf(acc[cm][nt][r] * inv);
      *(s16x4*)(amatT + ((size_t)b * L + tw + nt * 16 + lr) * C + h * 64 +
                cm * 16 + g * 4) = pk;
    }
  }
}

// ------------- Kernel 4: proj MFMA GEMM + bias + residual (fp32 x) ---------
__global__ __launch_bounds__(256) void proj_mfma(const short* __restrict__ pw,
    const float* __restrict__ bias, const short* __restrict__ amatT,
    const float* __restrict__ xres, float* __restrict__ out) {
  int tid = threadIdx.x;
  int wid = tid >> 6, lane = tid & 63, g = lane >> 4, lr = lane & 15;
  int o0 = blockIdx.y * 64;
  int b  = blockIdx.z;
  int lw = blockIdx.x * 128 + wid * 32;
  const short* ab = amatT + (size_t)b * L * C;

  f32x4 acc[4][2];
  #pragma unroll
  for (int m = 0; m < 4; ++m)
    #pragma unroll
    for (int nt = 0; nt < 2; ++nt) acc[m][nt] = (f32x4)0.f;

  #pragma unroll 2
  for (int k0 = 0; k0 < C; k0 += 32) {
    bf16x8 af[4], bfr[2];
    #pragma unroll
    for (int m = 0; m < 4; ++m)
      af[m] = *(const bf16x8*)(pw + (size_t)(o0 + m * 16 + lr) * C + k0 + g * 8);
    #pragma unroll
    for (int nt = 0; nt < 2; ++nt)
      bfr[nt] = *(const bf16x8*)(ab + (size_t)(lw + nt * 16 + lr) * C + k0 + g * 8);
    #pragma unroll
    for (int m = 0; m < 4; ++m)
      #pragma unroll
      for (int nt = 0; nt < 2; ++nt)
        acc[m][nt] = MFMA16(af[m], bfr[nt], acc[m][nt]);
  }

  #pragma unroll
  for (int m = 0; m < 4; ++m)
    #pragma unroll
    for (int nt = 0; nt < 2; ++nt)
      #pragma unroll
      for (int r = 0; r < 4; ++r) {
        int o = o0 + m * 16 + g * 4 + r;
        size_t idx = ((size_t)b * C + o) * L + lw + nt * 16 + lr;
        out[idx] = acc[m][nt][r] + bias[o] + xres[idx];
      }
}

// ---------------------------- launcher ----------------------------
extern "C" void kernel_launch(void* const* d_in, const int* in_sizes, int n_in,
                              void* d_out, int out_size, void* d_ws, size_t ws_size,
                              hipStream_t stream) {
  const float* x      = (const float*)d_in[0];
  const float* gn_w   = (const float*)d_in[1];
  const float* gn_b   = (const float*)d_in[2];
  const float* qkv_w  = (const float*)d_in[3];
  const float* qkv_b  = (const float*)d_in[4];
  const float* proj_w = (const float*)d_in[5];
  const float* proj_b = (const float*)d_in[6];
  float* out = (float*)d_out;

  short* xnT   = (short*)d_ws;                        // 8 MB
  short* qT    = xnT   + (size_t)4 * L * C;           // 8 MB
  short* kT    = qT    + (size_t)16 * L * 64;         // 8 MB
  short* vB    = kT    + (size_t)16 * L * 64;         // 8 MB
  short* amatT = vB    + (size_t)16 * L * 64;         // 8 MB
  short* xbf   = amatT + (size_t)4 * L * C;           // 8 MB
  short* wqbf  = xbf   + (size_t)4 * C * L;           // 384 KB
  short* pwbf  = wqbf  + (size_t)768 * C;             // 128 KB
  float* gnp   = (float*)(pwbf + (size_t)C * C);      // 4 KB

  prep<<<1536, 256, 0, stream>>>(x, gnp, xbf, qkv_w, proj_w, wqbf, pwbf);
  gn_apply<<<dim3(64, 4), 256, 0, stream>>>(xbf, gn_w, gn_b, gnp, xnT);
  qkv_mfma<<<dim3(32, 12, 4), 256, 0, stream>>>(wqbf, qkv_b, xnT, qT, kT, vB);
  attn_mfma<<<256, 512, 0, stream>>>(qT, kT, vB, amatT);
  proj_mfma<<<dim3(32, 4, 4), 256, 0, stream>>>(pwbf, proj_b, amatT, x, out);
}